// Round 12
// baseline (571.755 us; speedup 1.0000x reference)
//
#include <hip/hip_runtime.h>

#define LNEPS 1e-5f
#define AEPS 1e-8f
#define SCALE_Q 0.036084391824351615f  // 768^-0.5

typedef unsigned int uint32;

__device__ inline unsigned short bfb(float f) {
  __bf16 h = (__bf16)f;
  unsigned short u;
  __builtin_memcpy(&u, &h, 2);
  return u;
}

// ---------------- one-time: cast inputs fp32 -> packed bf16 (uint = 2 elems) ----------------
__global__ void cast_k(const float* __restrict__ in, uint32* __restrict__ xh) {
  size_t i = (size_t)blockIdx.x * 256 + threadIdx.x;  // 6291456 float4s
  float4 v = ((const float4*)in)[i];
  uint2 o;
  o.x = (uint32)bfb(v.x) | ((uint32)bfb(v.y) << 16);
  o.y = (uint32)bfb(v.z) | ((uint32)bfb(v.w) << 16);
  ((uint2*)xh)[i] = o;
}

// ---------------- transpose 768x768 fp32: WT[c][i] = W[i][c] ----------------
__global__ void packT_k(const float* __restrict__ W, float* __restrict__ WT) {
  __shared__ float tile[32][33];
  int c0 = blockIdx.x * 32, i0 = blockIdx.y * 32;
  int tx = threadIdx.x & 31, ty = threadIdx.x >> 5;  // 32x8
#pragma unroll
  for (int k = 0; k < 4; ++k)
    tile[ty + 8 * k][tx] = W[(size_t)(i0 + ty + 8 * k) * 768 + c0 + tx];
  __syncthreads();
#pragma unroll
  for (int k = 0; k < 4; ++k)
    WT[(size_t)(c0 + ty + 8 * k) * 768 + i0 + tx] = tile[tx][ty + 8 * k];
}

// ---------------- broadcast slots to all batch rows ----------------
__global__ void init_slots_k(const float* __restrict__ s0, float* __restrict__ slots) {
  int idx = blockIdx.x * 256 + threadIdx.x;  // 196608
  slots[idx] = s0[idx % 6144];
}

// ---------------- one-time small vectors: vb = bq@WkT ; wqbk = Wq@bk ; bqbk ----------------
__global__ void prep_vec_k(const float* __restrict__ Wq, const float* __restrict__ WkT,
                           const float* __restrict__ bq, const float* __restrict__ bk,
                           float* __restrict__ vb, float* __restrict__ wqbk,
                           float* __restrict__ bqbk) {
  int bb = blockIdx.x, t = threadIdx.x;
  if (bb < 3) {
    int d = bb * 256 + t;
    float a = 0.f;
    for (int k = 0; k < 768; ++k) a += bq[k] * WkT[(size_t)k * 768 + d];
    vb[d] = a;
  } else if (bb < 15) {
    int w = t >> 6, l = t & 63;
    for (int i = 0; i < 16; ++i) {
      int r = (bb - 3) * 64 + w * 16 + i;
      float a = 0.f;
#pragma unroll
      for (int j = 0; j < 12; ++j) { int c = l + 64 * j; a += Wq[(size_t)r * 768 + c] * bk[c]; }
#pragma unroll
      for (int o = 32; o; o >>= 1) a += __shfl_xor(a, o);
      if (l == 0) wqbk[r] = a;
    }
  } else if (t < 64) {
    int l = t;
    float a = 0.f;
#pragma unroll
    for (int j = 0; j < 12; ++j) { int c = l + 64 * j; a += bq[c] * bk[c]; }
#pragma unroll
    for (int o = 32; o; o >>= 1) a += __shfl_xor(a, o);
    if (l == 0) bqbk[0] = a;
  }
}

// ---------------- generic batched GEMV, grid (24 colblk, Nrow/8), 256 thr ----------------
// 8 rows x 32 cols per block; thread: cx=t&7 (4 cols), rw=(t>>3)&7, kg=t>>6 (192 k each).
// MODE 0: acc+bias | 1: acc | 2: alpha[r]*acc+beta[r]*bias | 3: relu(acc+bias) | 4: out+=acc+bias
template <bool LN, int MODE>
__global__ void gemv_k(const float* __restrict__ X, const float* __restrict__ W,
                       const float* __restrict__ bias, const float* __restrict__ gamma,
                       const float* __restrict__ beta_ln, const float* __restrict__ alpha,
                       const float* __restrict__ beta, float* __restrict__ out) {
  __shared__ float Xs[8][772];
  __shared__ float sm[8], sr[8];
  int c0 = blockIdx.x * 32, r0 = blockIdx.y * 8, t = threadIdx.x;
#pragma unroll
  for (int j = 0; j < 6; ++j) {
    int fidx = j * 256 + t;  // 1536 float4s
    int r = fidx / 192, c4 = fidx % 192;
    *(float4*)&Xs[r][c4 * 4] = *(const float4*)(X + (size_t)(r0 + r) * 768 + c4 * 4);
  }
  __syncthreads();
  if (LN) {
    int w = t >> 6, l = t & 63;
#pragma unroll
    for (int jr = 0; jr < 2; ++jr) {
      int r = w + 4 * jr;
      float s = 0.f, ss = 0.f;
#pragma unroll
      for (int m2 = 0; m2 < 12; ++m2) { float x = Xs[r][l + 64 * m2]; s += x; ss += x * x; }
#pragma unroll
      for (int o = 32; o; o >>= 1) { s += __shfl_xor(s, o); ss += __shfl_xor(ss, o); }
      if (l == 0) {
        float mu = s * (1.f / 768.f);
        sm[r] = mu;
        sr[r] = rsqrtf(ss * (1.f / 768.f) - mu * mu + LNEPS);
      }
    }
    __syncthreads();
#pragma unroll
    for (int j = 0; j < 24; ++j) {
      int idx = j * 256 + t;  // 6144
      int r = idx / 768, d = idx % 768;
      Xs[r][d] = (Xs[r][d] - sm[r]) * sr[r] * gamma[d] + beta_ln[d];
    }
    __syncthreads();
  }
  int cx = t & 7, rw = (t >> 3) & 7, kg = t >> 6;
  int c = c0 + cx * 4;
  float ax = 0.f, ay = 0.f, az = 0.f, aw = 0.f;
  const float* wp = W + c;
  int k0 = kg * 192;
  for (int k = k0; k < k0 + 192; k += 4) {
#pragma unroll
    for (int kk = 0; kk < 4; ++kk) {
      float4 wv = *(const float4*)(wp + (size_t)(k + kk) * 768);
      float xv = Xs[rw][k + kk];
      ax += xv * wv.x; ay += xv * wv.y; az += xv * wv.z; aw += xv * wv.w;
    }
  }
  __syncthreads();  // all kg done reading Xs; reuse as reduce buffer
  float* red = (float*)Xs;
  if (kg > 0) {
    float4 v; v.x = ax; v.y = ay; v.z = az; v.w = aw;
    *(float4*)&red[(size_t)(((kg - 1) * 64 + rw * 8 + cx)) * 4] = v;
  }
  __syncthreads();
  if (kg == 0) {
#pragma unroll
    for (int g = 1; g < 4; ++g) {
      float4 v = *(const float4*)&red[(size_t)(((g - 1) * 64 + rw * 8 + cx)) * 4];
      ax += v.x; ay += v.y; az += v.z; aw += v.w;
    }
    int rr = r0 + rw;
    size_t oidx = (size_t)rr * 768 + c;
    float4 res;
    if (MODE == 0) {
      float4 b4 = *(const float4*)(bias + c);
      res.x = ax + b4.x; res.y = ay + b4.y; res.z = az + b4.z; res.w = aw + b4.w;
    } else if (MODE == 1) {
      res.x = ax; res.y = ay; res.z = az; res.w = aw;
    } else if (MODE == 2) {
      float4 b4 = *(const float4*)(bias + c);
      float al = alpha[rr], be = beta[rr];
      res.x = ax * al + b4.x * be; res.y = ay * al + b4.y * be;
      res.z = az * al + b4.z * be; res.w = aw * al + b4.w * be;
    } else if (MODE == 3) {
      float4 b4 = *(const float4*)(bias + c);
      res.x = fmaxf(ax + b4.x, 0.f); res.y = fmaxf(ay + b4.y, 0.f);
      res.z = fmaxf(az + b4.z, 0.f); res.w = fmaxf(aw + b4.w, 0.f);
    } else {
      float4 b4 = *(const float4*)(bias + c);
      float4 old = *(const float4*)(out + oidx);
      res.x = old.x + ax + b4.x; res.y = old.y + ay + b4.y;
      res.z = old.z + az + b4.z; res.w = old.w + aw + b4.w;
    }
    *(float4*)(out + oidx) = res;
  }
}

// ---------------- per-slot scalars (LN inline): Sq = qk.g_in ; c0 = qk.b_in + sn.wqbk + bqbk
__global__ void qprep2_k(const float* __restrict__ slots, const float* __restrict__ g_s,
                         const float* __restrict__ b_s, const float* __restrict__ qk,
                         const float* __restrict__ g_in, const float* __restrict__ b_in,
                         const float* __restrict__ wqbk, const float* __restrict__ bqbk,
                         float* __restrict__ Sqbuf, float* __restrict__ c0buf) {
  int row = blockIdx.x * 4 + (threadIdx.x >> 6), l = threadIdx.x & 63;
  const float* sr = slots + (size_t)row * 768;
  float v[12], s = 0.f, ss = 0.f;
#pragma unroll
  for (int j = 0; j < 12; ++j) { v[j] = sr[l + 64 * j]; s += v[j]; ss += v[j] * v[j]; }
#pragma unroll
  for (int o = 32; o; o >>= 1) { s += __shfl_xor(s, o); ss += __shfl_xor(ss, o); }
  float mu = s * (1.f / 768.f), rs = rsqrtf(ss * (1.f / 768.f) - mu * mu + LNEPS);
  float aW = 0.f, aS = 0.f, aC = 0.f;
#pragma unroll
  for (int j = 0; j < 12; ++j) {
    int d = l + 64 * j;
    float sn = (v[j] - mu) * rs * g_s[d] + b_s[d];
    aW += sn * wqbk[d];
    float qkv = qk[(size_t)row * 768 + d];
    aS += qkv * g_in[d];
    aC += qkv * b_in[d];
  }
#pragma unroll
  for (int o = 32; o; o >>= 1) {
    aW += __shfl_xor(aW, o); aS += __shfl_xor(aS, o); aC += __shfl_xor(aC, o);
  }
  if (l == 0) { Sqbuf[row] = aS; c0buf[row] = aC + aW + bqbk[0]; }
}

// ---------------- dots+softmax over packed-bf16 x; attn, w=a*r, rmu=r*mu ----------------
// grid (16 chunk, 32 b), 256 thr = 4 waves x 16 rows each (64 rows/block).
__global__ void __launch_bounds__(256, 2)
dots_k(const uint32* __restrict__ xh, const float* __restrict__ qk,
       const float* __restrict__ g_in, const float* __restrict__ Sqbuf,
       const float* __restrict__ c0buf, float* __restrict__ attnbuf,
       float* __restrict__ wbuf, float* __restrict__ rmubuf) {
  __shared__ float qkgs[8][768];
  __shared__ float c0s[8], Sqs[8];
  __shared__ float oa[64][8], ow[64][8], orm[64];
  int chunk = blockIdx.x, b = blockIdx.y, t = threadIdx.x, w = t >> 6, l = t & 63;
#pragma unroll
  for (int s2 = 0; s2 < 8; ++s2)
    for (int d = t; d < 768; d += 256)
      qkgs[s2][d] = qk[(size_t)b * 6144 + s2 * 768 + d] * g_in[d];
  if (t < 8) { c0s[t] = c0buf[b * 8 + t]; Sqs[t] = Sqbuf[b * 8 + t]; }
  __syncthreads();
  for (int rr = 0; rr < 16; ++rr) {
    int lr = w * 16 + rr;  // local row 0..63
    size_t row = (size_t)b * 1024 + chunk * 64 + lr;
    const uint32* xr = xh + row * 384;
    float s = 0.f, ss = 0.f, ds[8] = {};
#pragma unroll
    for (int j = 0; j < 6; ++j) {
      uint32 u = xr[l + 64 * j];
      float a = __uint_as_float(u << 16);
      float bv = __uint_as_float(u & 0xffff0000u);
      s += a + bv;
      ss += a * a + bv * bv;
      int d0 = 2 * (l + 64 * j);
#pragma unroll
      for (int s2 = 0; s2 < 8; ++s2) {
        float2 qg = *(const float2*)&qkgs[s2][d0];
        ds[s2] += qg.x * a + qg.y * bv;
      }
    }
#pragma unroll
    for (int o = 32; o; o >>= 1) {
      s += __shfl_xor(s, o);
      ss += __shfl_xor(ss, o);
#pragma unroll
      for (int s2 = 0; s2 < 8; ++s2) ds[s2] += __shfl_xor(ds[s2], o);
    }
    float mu = s * (1.f / 768.f), r = rsqrtf(ss * (1.f / 768.f) - mu * mu + LNEPS);
    float rmu = r * mu;
    float sc[8];
#pragma unroll
    for (int s2 = 0; s2 < 8; ++s2)
      sc[s2] = (r * ds[s2] - rmu * Sqs[s2] + c0s[s2]) * SCALE_Q;
    float mx = sc[0];
#pragma unroll
    for (int s2 = 1; s2 < 8; ++s2) mx = fmaxf(mx, sc[s2]);
    float e[8], se = 0.f;
#pragma unroll
    for (int s2 = 0; s2 < 8; ++s2) { e[s2] = __expf(sc[s2] - mx); se += e[s2]; }
    float inv_se = 1.f / se;
    float a = e[0];
#pragma unroll
    for (int s2 = 1; s2 < 8; ++s2) a = (l == s2) ? e[s2] : a;
    a *= inv_se;
    if (l < 8) {
      oa[lr][l] = a;
      ow[lr][l] = a * r;
    }
    if (l == 8) orm[lr] = rmu;
  }
  __syncthreads();
  size_t base8 = ((size_t)b * 1024 + chunk * 64) * 8;
#pragma unroll
  for (int i = 0; i < 2; ++i) {
    int idx = t + 256 * i;
    attnbuf[base8 + idx] = oa[idx >> 3][idx & 7];
    wbuf[base8 + idx] = ow[idx >> 3][idx & 7];
  }
  if (t < 64) rmubuf[(size_t)b * 1024 + chunk * 64 + t] = orm[t];
}

// ---------------- pool packed-bf16 x with weights w -> partials[chunk][b*8+s][768] -------
// grid (16 chunk, 32 b), 384 thr: thread owns packed col t (d=2t,2t+1)
__global__ void pool_k(const uint32* __restrict__ xh, const float* __restrict__ wbuf,
                       float* __restrict__ partials) {
  __shared__ float ws[64][8];
  int chunk = blockIdx.x, b = blockIdx.y, t = threadIdx.x;
  for (int i = t; i < 512; i += 384)
    ((float*)ws)[i] = wbuf[((size_t)b * 1024 + chunk * 64) * 8 + i];
  __syncthreads();
  float acc[8][2] = {};
  const uint32* xp = xh + ((size_t)b * 1024 + chunk * 64) * 384;
  for (int nn = 0; nn < 64; ++nn) {
    uint32 u = xp[(size_t)nn * 384 + t];
    float x0 = __uint_as_float(u << 16);
    float x1 = __uint_as_float(u & 0xffff0000u);
#pragma unroll
    for (int s2 = 0; s2 < 8; ++s2) {
      float wv = ws[nn][s2];
      acc[s2][0] += wv * x0; acc[s2][1] += wv * x1;
    }
  }
#pragma unroll
  for (int s2 = 0; s2 < 8; ++s2) {
    size_t base = ((size_t)(chunk * 256 + b * 8 + s2)) * 768;
    float2 v; v.x = acc[s2][0]; v.y = acc[s2][1];
    *(float2*)&partials[base + 2 * t] = v;
  }
}

// ---------------- reduce partials + A0/A1 + LN-fixup -> pooled ; inv, rho ----------------
// grid 256 (row = b*8+s), 256 thr
__global__ void reduce_fix_k(const float* __restrict__ partials, const float* __restrict__ attnbuf,
                             const float* __restrict__ rmubuf, const float* __restrict__ g_in,
                             const float* __restrict__ b_in, float* __restrict__ pooled,
                             float* __restrict__ invbuf, float* __restrict__ rhobuf) {
  __shared__ float rA[4], rB[4], sAB[2];
  int row = blockIdx.x, t = threadIdx.x;  // row = b*8+s
  int b = row >> 3, sl = row & 7;
  float a0 = 0.f, a1 = 0.f;
#pragma unroll
  for (int j = 0; j < 4; ++j) {
    int n = t + 256 * j;
    float a = attnbuf[((size_t)b * 1024 + n) * 8 + sl];
    a0 += a;
    a1 += a * rmubuf[b * 1024 + n];
  }
#pragma unroll
  for (int o = 32; o; o >>= 1) { a0 += __shfl_xor(a0, o); a1 += __shfl_xor(a1, o); }
  if ((t & 63) == 0) { rA[t >> 6] = a0; rB[t >> 6] = a1; }
  __syncthreads();
  if (t == 0) {
    sAB[0] = rA[0] + rA[1] + rA[2] + rA[3];
    sAB[1] = rB[0] + rB[1] + rB[2] + rB[3];
  }
  __syncthreads();
  float A0 = sAB[0], A1 = sAB[1];
#pragma unroll
  for (int c = 0; c < 3; ++c) {
    int d = t + 256 * c;
    float a = 0.f;
    for (int ch = 0; ch < 16; ++ch) a += partials[((size_t)(ch * 256 + row)) * 768 + d];
    pooled[(size_t)row * 768 + d] = g_in[d] * (a - A1) + b_in[d] * A0;
  }
  if (t == 0) {
    float iv = 1.f / (A0 + AEPS);
    invbuf[row] = iv;
    rhobuf[row] = A0 * iv;
  }
}

// ---------------- merged output writer (fp32) ----------------
__global__ void outs_k(const float* __restrict__ slots, const float* __restrict__ attnbuf,
                       const float* __restrict__ invbuf, float* __restrict__ out) {
  int i = blockIdx.x * 256 + threadIdx.x;  // 458752
  if (i < 196608) {
    out[i] = slots[i];
  } else {
    int j = i - 196608;  // [b][n][s]
    out[i] = attnbuf[j] * invbuf[((j >> 13) << 3) + (j & 7)];
  }
}

extern "C" void kernel_launch(void* const* d_in, const int* in_sizes, int n_in,
                              void* d_out, int out_size, void* d_ws, size_t ws_size,
                              hipStream_t stream) {
  (void)in_sizes; (void)n_in; (void)out_size; (void)ws_size;
  const float* slots0 = (const float*)d_in[0];
  const float* inputs = (const float*)d_in[1];
  const float* Wq = (const float*)d_in[2];
  const float* bq = (const float*)d_in[3];
  const float* Wk = (const float*)d_in[4];
  const float* bk = (const float*)d_in[5];
  const float* Wv = (const float*)d_in[6];
  const float* bv = (const float*)d_in[7];
  const float* g_in = (const float*)d_in[8];
  const float* b_in = (const float*)d_in[9];
  const float* g_s = (const float*)d_in[10];
  const float* b_s = (const float*)d_in[11];
  const float* g_ff = (const float*)d_in[12];
  const float* b_ff = (const float*)d_in[13];
  const float* W1 = (const float*)d_in[14];
  const float* b1 = (const float*)d_in[15];
  const float* W2 = (const float*)d_in[16];
  const float* b2 = (const float*)d_in[17];

  char* p = (char*)d_ws;
  uint32* xh = (uint32*)p;     p += (size_t)32768 * 384 * 4;  // packed bf16 inputs
  float* WkT = (float*)p;      p += (size_t)768 * 768 * 4;
  float* Mqk = (float*)p;      p += (size_t)768 * 768 * 4;    // Wq @ WkT
  float* vb = (float*)p;       p += 768 * 4;
  float* wqbk = (float*)p;     p += 768 * 4;
  float* bqbk = (float*)p;     p += 4 * 4;
  float* slotsf = (float*)p;   p += 256 * 768 * 4;
  float* qkbuf = (float*)p;    p += 256 * 768 * 4;
  float* Sqbuf = (float*)p;    p += 256 * 4;
  float* c0buf = (float*)p;    p += 256 * 4;
  float* attnbuf = (float*)p;  p += (size_t)32768 * 8 * 4;
  float* wbuf = (float*)p;     p += (size_t)32768 * 8 * 4;
  float* rmubuf = (float*)p;   p += 32768 * 4;
  float* partials = (float*)p; p += (size_t)16 * 256 * 768 * 4;
  float* pooled = (float*)p;   p += 256 * 768 * 4;
  float* invbuf = (float*)p;   p += 256 * 4;
  float* rhobuf = (float*)p;   p += 256 * 4;
  float* updbuf = (float*)p;   p += 256 * 768 * 4;
  float* t1buf = (float*)p;    p += 256 * 768 * 4;

  dim3 ggrid(24, 32);
  cast_k<<<24576, 256, 0, stream>>>(inputs, xh);
  packT_k<<<dim3(24, 24), 256, 0, stream>>>(Wk, WkT);
  gemv_k<false, 1><<<dim3(24, 96), 256, 0, stream>>>(Wq, WkT, nullptr, nullptr, nullptr,
                                                     nullptr, nullptr, Mqk);
  prep_vec_k<<<16, 256, 0, stream>>>(Wq, WkT, bq, bk, vb, wqbk, bqbk);
  init_slots_k<<<768, 256, 0, stream>>>(slots0, slotsf);
  for (int it = 0; it < 3; ++it) {
    gemv_k<true, 0><<<ggrid, 256, 0, stream>>>(slotsf, Mqk, vb, g_s, b_s, nullptr, nullptr,
                                               qkbuf);
    qprep2_k<<<64, 256, 0, stream>>>(slotsf, g_s, b_s, qkbuf, g_in, b_in, wqbk, bqbk,
                                     Sqbuf, c0buf);
    dots_k<<<dim3(16, 32), 256, 0, stream>>>(xh, qkbuf, g_in, Sqbuf, c0buf, attnbuf, wbuf,
                                             rmubuf);
    pool_k<<<dim3(16, 32), 384, 0, stream>>>(xh, wbuf, partials);
    reduce_fix_k<<<256, 256, 0, stream>>>(partials, attnbuf, rmubuf, g_in, b_in, pooled,
                                          invbuf, rhobuf);
    gemv_k<false, 2><<<ggrid, 256, 0, stream>>>(pooled, Wv, bv, nullptr, nullptr, invbuf,
                                                rhobuf, updbuf);
    gemv_k<true, 3><<<ggrid, 256, 0, stream>>>(updbuf, W1, b1, g_ff, b_ff, nullptr, nullptr,
                                               t1buf);
    gemv_k<false, 4><<<ggrid, 256, 0, stream>>>(t1buf, W2, b2, nullptr, nullptr, nullptr,
                                                nullptr, slotsf);
  }
  outs_k<<<1792, 256, 0, stream>>>(slotsf, attnbuf, invbuf, (float*)d_out);
}

// Round 13
// 524.749 us; speedup vs baseline: 1.0896x; 1.0896x over previous
//
#include <hip/hip_runtime.h>

#define LNEPS 1e-5f
#define AEPS 1e-8f
#define SCALE_Q 0.036084391824351615f  // 768^-0.5

typedef unsigned int uint32;

__device__ inline unsigned short bfb(float f) {
  __bf16 h = (__bf16)f;
  unsigned short u;
  __builtin_memcpy(&u, &h, 2);
  return u;
}

// ---------------- one-time: cast inputs fp32 -> packed bf16 (uint = 2 elems) ----------------
__global__ void cast_k(const float* __restrict__ in, uint32* __restrict__ xh) {
  size_t i = (size_t)blockIdx.x * 256 + threadIdx.x;  // 6291456 float4s
  float4 v = ((const float4*)in)[i];
  uint2 o;
  o.x = (uint32)bfb(v.x) | ((uint32)bfb(v.y) << 16);
  o.y = (uint32)bfb(v.z) | ((uint32)bfb(v.w) << 16);
  ((uint2*)xh)[i] = o;
}

// ---------------- transpose 768x768 fp32: WT[c][i] = W[i][c] ----------------
__global__ void packT_k(const float* __restrict__ W, float* __restrict__ WT) {
  __shared__ float tile[32][33];
  int c0 = blockIdx.x * 32, i0 = blockIdx.y * 32;
  int tx = threadIdx.x & 31, ty = threadIdx.x >> 5;  // 32x8
#pragma unroll
  for (int k = 0; k < 4; ++k)
    tile[ty + 8 * k][tx] = W[(size_t)(i0 + ty + 8 * k) * 768 + c0 + tx];
  __syncthreads();
#pragma unroll
  for (int k = 0; k < 4; ++k)
    WT[(size_t)(c0 + ty + 8 * k) * 768 + i0 + tx] = (float)tile[tx][ty + 8 * k];
}

// ---------------- broadcast slots to all batch rows ----------------
__global__ void init_slots_k(const float* __restrict__ s0, float* __restrict__ slots) {
  int idx = blockIdx.x * 256 + threadIdx.x;  // 196608
  slots[idx] = s0[idx % 6144];
}

// ---------------- batched GEMV v2: coalesced col-per-thread, 512 thr, grid (6,32) --------
// Thread: c = bx*128 + (t&127); kg = t>>7 (k in [kg*192, +192)); rows r0=by*8..+8.
// X staged transposed XsT[k][8] (stride 12 floats); W reads fully coalesced (1 dword/lane).
// MODE 0: acc+bias | 1: acc | 2: alpha[r]*acc+beta[r]*bias | 3: relu(acc+bias) | 4: out+=acc+bias
template <bool LN, int MODE>
__global__ void gemv_k(const float* __restrict__ X, const float* __restrict__ W,
                       const float* __restrict__ bias, const float* __restrict__ gamma,
                       const float* __restrict__ beta_ln, const float* __restrict__ alpha,
                       const float* __restrict__ beta, float* __restrict__ out) {
  __shared__ float XsT[768 * 12];  // [k][r] stride 12 (pad: 2-way banks on stage writes)
  int t = threadIdx.x;
  int c0 = blockIdx.x * 128, r0 = blockIdx.y * 8;
  // stage 8 rows x 768, transposed
#pragma unroll
  for (int j = 0; j < 3; ++j) {
    int fidx = j * 512 + t;  // 0..1535
    int r = fidx / 192, c4 = fidx % 192;
    float4 v = *(const float4*)(X + (size_t)(r0 + r) * 768 + c4 * 4);
    int kb = c4 * 4;
    XsT[(kb + 0) * 12 + r] = v.x;
    XsT[(kb + 1) * 12 + r] = v.y;
    XsT[(kb + 2) * 12 + r] = v.z;
    XsT[(kb + 3) * 12 + r] = v.w;
  }
  __syncthreads();
  if (LN) {
    int w = t >> 6, l = t & 63;  // 8 waves, one row each
    float s = 0.f, ss = 0.f;
#pragma unroll
    for (int m = 0; m < 12; ++m) {
      float x = XsT[(l + 64 * m) * 12 + w];
      s += x; ss += x * x;
    }
#pragma unroll
    for (int o = 32; o; o >>= 1) { s += __shfl_xor(s, o); ss += __shfl_xor(ss, o); }
    float mu = s * (1.f / 768.f), rs = rsqrtf(ss * (1.f / 768.f) - mu * mu + LNEPS);
#pragma unroll
    for (int m = 0; m < 12; ++m) {
      int d = l + 64 * m;
      XsT[d * 12 + w] = (XsT[d * 12 + w] - mu) * rs * gamma[d] + beta_ln[d];
    }
    __syncthreads();
  }
  int cx = t & 127, kg = t >> 7;
  int c = c0 + cx;
  float acc[8] = {};
  const float* wp = W + c;
  int k0 = kg * 192;
#pragma unroll 4
  for (int k = k0; k < k0 + 192; ++k) {
    float wv = wp[(size_t)k * 768];
    float4 xa = *(const float4*)&XsT[k * 12];
    float4 xb = *(const float4*)&XsT[k * 12 + 4];
    acc[0] += xa.x * wv; acc[1] += xa.y * wv; acc[2] += xa.z * wv; acc[3] += xa.w * wv;
    acc[4] += xb.x * wv; acc[5] += xb.y * wv; acc[6] += xb.z * wv; acc[7] += xb.w * wv;
  }
  __syncthreads();  // done reading XsT; reuse as reduce buffer (need 3072 < 9216 floats)
  float* red = XsT;
  if (kg > 0) {
#pragma unroll
    for (int r = 0; r < 8; ++r) red[((kg - 1) * 8 + r) * 128 + cx] = acc[r];
  }
  __syncthreads();
  if (kg == 0) {
#pragma unroll
    for (int g = 1; g < 4; ++g)
#pragma unroll
      for (int r = 0; r < 8; ++r) acc[r] += red[((g - 1) * 8 + r) * 128 + cx];
    float bsc = (MODE == 1) ? 0.f : bias[c];
#pragma unroll
    for (int r = 0; r < 8; ++r) {
      int rr = r0 + r;
      size_t oidx = (size_t)rr * 768 + c;
      float v;
      if (MODE == 0) v = acc[r] + bsc;
      else if (MODE == 1) v = acc[r];
      else if (MODE == 2) v = acc[r] * alpha[rr] + bsc * beta[rr];
      else if (MODE == 3) v = fmaxf(acc[r] + bsc, 0.f);
      else v = out[oidx] + acc[r] + bsc;
      out[oidx] = v;
    }
  }
}

// ---------------- per-slot scalars: Sq = qk.g_in ; c0 = qk.b_in + q.bk ----------------
__global__ void qprep_k(const float* __restrict__ q, const float* __restrict__ qk,
                        const float* __restrict__ g_in, const float* __restrict__ b_in,
                        const float* __restrict__ bk, float* __restrict__ Sqbuf,
                        float* __restrict__ c0buf) {
  int row = blockIdx.x * 4 + (threadIdx.x >> 6), l = threadIdx.x & 63;
  float aS = 0.f, aC = 0.f;
#pragma unroll
  for (int j = 0; j < 12; ++j) {
    int d = l + 64 * j;
    float qkv = qk[(size_t)row * 768 + d];
    aS += qkv * g_in[d];
    aC += qkv * b_in[d] + q[(size_t)row * 768 + d] * bk[d];
  }
#pragma unroll
  for (int o = 32; o; o >>= 1) { aS += __shfl_xor(aS, o); aC += __shfl_xor(aC, o); }
  if (l == 0) { Sqbuf[row] = aS; c0buf[row] = aC; }
}

// ---------------- dots+softmax over packed-bf16 x; attn, w=a*r, rmu=r*mu ----------------
// grid (16 chunk, 32 b), 256 thr = 4 waves x 16 rows each (64 rows/block).
__global__ void __launch_bounds__(256, 2)
dots_k(const uint32* __restrict__ xh, const float* __restrict__ qk,
       const float* __restrict__ g_in, const float* __restrict__ Sqbuf,
       const float* __restrict__ c0buf, float* __restrict__ attnbuf,
       float* __restrict__ wbuf, float* __restrict__ rmubuf) {
  __shared__ float qkgs[8][768];
  __shared__ float c0s[8], Sqs[8];
  __shared__ float oa[64][8], ow[64][8], orm[64];
  int chunk = blockIdx.x, b = blockIdx.y, t = threadIdx.x, w = t >> 6, l = t & 63;
#pragma unroll
  for (int s2 = 0; s2 < 8; ++s2)
    for (int d = t; d < 768; d += 256)
      qkgs[s2][d] = qk[(size_t)b * 6144 + s2 * 768 + d] * g_in[d];
  if (t < 8) { c0s[t] = c0buf[b * 8 + t]; Sqs[t] = Sqbuf[b * 8 + t]; }
  __syncthreads();
  for (int rr = 0; rr < 16; ++rr) {
    int lr = w * 16 + rr;  // local row 0..63
    size_t row = (size_t)b * 1024 + chunk * 64 + lr;
    const uint32* xr = xh + row * 384;
    float s = 0.f, ss = 0.f, ds[8] = {};
#pragma unroll
    for (int j = 0; j < 6; ++j) {
      uint32 u = xr[l + 64 * j];
      float a = __uint_as_float(u << 16);
      float bv = __uint_as_float(u & 0xffff0000u);
      s += a + bv;
      ss += a * a + bv * bv;
      int d0 = 2 * (l + 64 * j);
#pragma unroll
      for (int s2 = 0; s2 < 8; ++s2) {
        float2 qg = *(const float2*)&qkgs[s2][d0];
        ds[s2] += qg.x * a + qg.y * bv;
      }
    }
#pragma unroll
    for (int o = 32; o; o >>= 1) {
      s += __shfl_xor(s, o);
      ss += __shfl_xor(ss, o);
#pragma unroll
      for (int s2 = 0; s2 < 8; ++s2) ds[s2] += __shfl_xor(ds[s2], o);
    }
    float mu = s * (1.f / 768.f), r = rsqrtf(ss * (1.f / 768.f) - mu * mu + LNEPS);
    float rmu = r * mu;
    float sc[8];
#pragma unroll
    for (int s2 = 0; s2 < 8; ++s2)
      sc[s2] = (r * ds[s2] - rmu * Sqs[s2] + c0s[s2]) * SCALE_Q;
    float mx = sc[0];
#pragma unroll
    for (int s2 = 1; s2 < 8; ++s2) mx = fmaxf(mx, sc[s2]);
    float e[8], se = 0.f;
#pragma unroll
    for (int s2 = 0; s2 < 8; ++s2) { e[s2] = __expf(sc[s2] - mx); se += e[s2]; }
    float inv_se = 1.f / se;
    float a = e[0];
#pragma unroll
    for (int s2 = 1; s2 < 8; ++s2) a = (l == s2) ? e[s2] : a;
    a *= inv_se;
    if (l < 8) {
      oa[lr][l] = a;
      ow[lr][l] = a * r;
    }
    if (l == 8) orm[lr] = rmu;
  }
  __syncthreads();
  size_t base8 = ((size_t)b * 1024 + chunk * 64) * 8;
#pragma unroll
  for (int i = 0; i < 2; ++i) {
    int idx = t + 256 * i;
    attnbuf[base8 + idx] = oa[idx >> 3][idx & 7];
    wbuf[base8 + idx] = ow[idx >> 3][idx & 7];
  }
  if (t < 64) rmubuf[(size_t)b * 1024 + chunk * 64 + t] = orm[t];
}

// ---------------- pool packed-bf16 x with weights w -> partials[chunk][b*8+s][768] -------
// grid (16 chunk, 32 b), 384 thr: thread owns packed col t (d=2t,2t+1)
__global__ void pool_k(const uint32* __restrict__ xh, const float* __restrict__ wbuf,
                       float* __restrict__ partials) {
  __shared__ float ws[64][8];
  int chunk = blockIdx.x, b = blockIdx.y, t = threadIdx.x;
  for (int i = t; i < 512; i += 384)
    ((float*)ws)[i] = wbuf[((size_t)b * 1024 + chunk * 64) * 8 + i];
  __syncthreads();
  float acc[8][2] = {};
  const uint32* xp = xh + ((size_t)b * 1024 + chunk * 64) * 384;
  for (int nn = 0; nn < 64; ++nn) {
    uint32 u = xp[(size_t)nn * 384 + t];
    float x0 = __uint_as_float(u << 16);
    float x1 = __uint_as_float(u & 0xffff0000u);
#pragma unroll
    for (int s2 = 0; s2 < 8; ++s2) {
      float wv = ws[nn][s2];
      acc[s2][0] += wv * x0; acc[s2][1] += wv * x1;
    }
  }
#pragma unroll
  for (int s2 = 0; s2 < 8; ++s2) {
    size_t base = ((size_t)(chunk * 256 + b * 8 + s2)) * 768;
    float2 v; v.x = acc[s2][0]; v.y = acc[s2][1];
    *(float2*)&partials[base + 2 * t] = v;
  }
}

// ---------------- reduce partials + A0/A1 + LN-fixup -> pooled ; inv, rho ----------------
// grid 256 (row = b*8+s), 256 thr
__global__ void reduce_fix_k(const float* __restrict__ partials, const float* __restrict__ attnbuf,
                             const float* __restrict__ rmubuf, const float* __restrict__ g_in,
                             const float* __restrict__ b_in, float* __restrict__ pooled,
                             float* __restrict__ invbuf, float* __restrict__ rhobuf) {
  __shared__ float rA[4], rB[4], sAB[2];
  int row = blockIdx.x, t = threadIdx.x;  // row = b*8+s
  int b = row >> 3, sl = row & 7;
  float a0 = 0.f, a1 = 0.f;
#pragma unroll
  for (int j = 0; j < 4; ++j) {
    int n = t + 256 * j;
    float a = attnbuf[((size_t)b * 1024 + n) * 8 + sl];
    a0 += a;
    a1 += a * rmubuf[b * 1024 + n];
  }
#pragma unroll
  for (int o = 32; o; o >>= 1) { a0 += __shfl_xor(a0, o); a1 += __shfl_xor(a1, o); }
  if ((t & 63) == 0) { rA[t >> 6] = a0; rB[t >> 6] = a1; }
  __syncthreads();
  if (t == 0) {
    sAB[0] = rA[0] + rA[1] + rA[2] + rA[3];
    sAB[1] = rB[0] + rB[1] + rB[2] + rB[3];
  }
  __syncthreads();
  float A0 = sAB[0], A1 = sAB[1];
#pragma unroll
  for (int c = 0; c < 3; ++c) {
    int d = t + 256 * c;
    float a = 0.f;
    for (int ch = 0; ch < 16; ++ch) a += partials[((size_t)(ch * 256 + row)) * 768 + d];
    pooled[(size_t)row * 768 + d] = g_in[d] * (a - A1) + b_in[d] * A0;
  }
  if (t == 0) {
    float iv = 1.f / (A0 + AEPS);
    invbuf[row] = iv;
    rhobuf[row] = A0 * iv;
  }
}

// ---------------- merged output writer (fp32) ----------------
__global__ void outs_k(const float* __restrict__ slots, const float* __restrict__ attnbuf,
                       const float* __restrict__ invbuf, float* __restrict__ out) {
  int i = blockIdx.x * 256 + threadIdx.x;  // 458752
  if (i < 196608) {
    out[i] = slots[i];
  } else {
    int j = i - 196608;  // [b][n][s]
    out[i] = attnbuf[j] * invbuf[((j >> 13) << 3) + (j & 7)];
  }
}

extern "C" void kernel_launch(void* const* d_in, const int* in_sizes, int n_in,
                              void* d_out, int out_size, void* d_ws, size_t ws_size,
                              hipStream_t stream) {
  (void)in_sizes; (void)n_in; (void)out_size; (void)ws_size;
  const float* slots0 = (const float*)d_in[0];
  const float* inputs = (const float*)d_in[1];
  const float* Wq = (const float*)d_in[2];
  const float* bq = (const float*)d_in[3];
  const float* Wk = (const float*)d_in[4];
  const float* bk = (const float*)d_in[5];
  const float* Wv = (const float*)d_in[6];
  const float* bv = (const float*)d_in[7];
  const float* g_in = (const float*)d_in[8];
  const float* b_in = (const float*)d_in[9];
  const float* g_s = (const float*)d_in[10];
  const float* b_s = (const float*)d_in[11];
  const float* g_ff = (const float*)d_in[12];
  const float* b_ff = (const float*)d_in[13];
  const float* W1 = (const float*)d_in[14];
  const float* b1 = (const float*)d_in[15];
  const float* W2 = (const float*)d_in[16];
  const float* b2 = (const float*)d_in[17];

  char* p = (char*)d_ws;
  uint32* xh = (uint32*)p;     p += (size_t)32768 * 384 * 4;  // packed bf16 inputs
  float* WkT = (float*)p;      p += (size_t)768 * 768 * 4;
  float* slotsf = (float*)p;   p += 256 * 768 * 4;
  float* qbuf = (float*)p;     p += 256 * 768 * 4;
  float* qkbuf = (float*)p;    p += 256 * 768 * 4;
  float* Sqbuf = (float*)p;    p += 256 * 4;
  float* c0buf = (float*)p;    p += 256 * 4;
  float* attnbuf = (float*)p;  p += (size_t)32768 * 8 * 4;
  float* wbuf = (float*)p;     p += (size_t)32768 * 8 * 4;
  float* rmubuf = (float*)p;   p += 32768 * 4;
  float* partials = (float*)p; p += (size_t)16 * 256 * 768 * 4;
  float* pooled = (float*)p;   p += 256 * 768 * 4;
  float* invbuf = (float*)p;   p += 256 * 4;
  float* rhobuf = (float*)p;   p += 256 * 4;
  float* updbuf = (float*)p;   p += 256 * 768 * 4;
  float* t1buf = (float*)p;    p += 256 * 768 * 4;

  dim3 ggrid(6, 32);
  cast_k<<<24576, 256, 0, stream>>>(inputs, xh);
  packT_k<<<dim3(24, 24), 256, 0, stream>>>(Wk, WkT);
  init_slots_k<<<768, 256, 0, stream>>>(slots0, slotsf);
  for (int it = 0; it < 3; ++it) {
    gemv_k<true, 0><<<ggrid, 512, 0, stream>>>(slotsf, Wq, bq, g_s, b_s, nullptr, nullptr,
                                               qbuf);
    gemv_k<false, 1><<<ggrid, 512, 0, stream>>>(qbuf, WkT, nullptr, nullptr, nullptr, nullptr,
                                                nullptr, qkbuf);
    qprep_k<<<64, 256, 0, stream>>>(qbuf, qkbuf, g_in, b_in, bk, Sqbuf, c0buf);
    dots_k<<<dim3(16, 32), 256, 0, stream>>>(xh, qkbuf, g_in, Sqbuf, c0buf, attnbuf, wbuf,
                                             rmubuf);
    pool_k<<<dim3(16, 32), 384, 0, stream>>>(xh, wbuf, partials);
    reduce_fix_k<<<256, 256, 0, stream>>>(partials, attnbuf, rmubuf, g_in, b_in, pooled,
                                          invbuf, rhobuf);
    gemv_k<false, 2><<<ggrid, 512, 0, stream>>>(pooled, Wv, bv, nullptr, nullptr, invbuf,
                                                rhobuf, updbuf);
    gemv_k<true, 3><<<ggrid, 512, 0, stream>>>(updbuf, W1, b1, g_ff, b_ff, nullptr, nullptr,
                                               t1buf);
    gemv_k<false, 4><<<ggrid, 512, 0, stream>>>(t1buf, W2, b2, nullptr, nullptr, nullptr,
                                                nullptr, slotsf);
  }
  outs_k<<<1792, 256, 0, stream>>>(slotsf, attnbuf, invbuf, (float*)d_out);
}

// Round 14
// 485.919 us; speedup vs baseline: 1.1766x; 1.0799x over previous
//
#include <hip/hip_runtime.h>

#define LNEPS 1e-5f
#define AEPS 1e-8f
#define SCALE_Q 0.036084391824351615f  // 768^-0.5

typedef unsigned int uint32;

__device__ inline unsigned short bfb(float f) {
  __bf16 h = (__bf16)f;
  unsigned short u;
  __builtin_memcpy(&u, &h, 2);
  return u;
}

// ---------------- one-time: cast inputs fp32 -> packed bf16 (uint = 2 elems) ----------------
__global__ void cast_k(const float* __restrict__ in, uint32* __restrict__ xh) {
  size_t i = (size_t)blockIdx.x * 256 + threadIdx.x;  // 6291456 float4s
  float4 v = ((const float4*)in)[i];
  uint2 o;
  o.x = (uint32)bfb(v.x) | ((uint32)bfb(v.y) << 16);
  o.y = (uint32)bfb(v.z) | ((uint32)bfb(v.w) << 16);
  ((uint2*)xh)[i] = o;
}

// ---------------- transpose 768x768 fp32: WT[c][i] = W[i][c] ----------------
__global__ void packT_k(const float* __restrict__ W, float* __restrict__ WT) {
  __shared__ float tile[32][33];
  int c0 = blockIdx.x * 32, i0 = blockIdx.y * 32;
  int tx = threadIdx.x & 31, ty = threadIdx.x >> 5;  // 32x8
#pragma unroll
  for (int k = 0; k < 4; ++k)
    tile[ty + 8 * k][tx] = W[(size_t)(i0 + ty + 8 * k) * 768 + c0 + tx];
  __syncthreads();
#pragma unroll
  for (int k = 0; k < 4; ++k)
    WT[(size_t)(c0 + ty + 8 * k) * 768 + i0 + tx] = tile[tx][ty + 8 * k];
}

// ---------------- broadcast slots to all batch rows ----------------
__global__ void init_slots_k(const float* __restrict__ s0, float* __restrict__ slots) {
  int idx = blockIdx.x * 256 + threadIdx.x;  // 196608
  slots[idx] = s0[idx % 6144];
}

// ---------------- batched GEMV v2: coalesced col-per-thread, 512 thr, grid (6,32) --------
// Thread: c = bx*128 + (t&127); kg = t>>7 (k in [kg*192, +192)); rows r0=by*8..+8.
// MODE 0: acc+bias | 1: acc | 2: alpha[r]*acc+beta[r]*bias | 3: relu(acc+bias) | 4: out+=acc+bias
template <bool LN, int MODE>
__global__ void gemv_k(const float* __restrict__ X, const float* __restrict__ W,
                       const float* __restrict__ bias, const float* __restrict__ gamma,
                       const float* __restrict__ beta_ln, const float* __restrict__ alpha,
                       const float* __restrict__ beta, float* __restrict__ out) {
  __shared__ float XsT[768 * 12];  // [k][r] stride 12
  int t = threadIdx.x;
  int c0 = blockIdx.x * 128, r0 = blockIdx.y * 8;
#pragma unroll
  for (int j = 0; j < 3; ++j) {
    int fidx = j * 512 + t;  // 0..1535
    int r = fidx / 192, c4 = fidx % 192;
    float4 v = *(const float4*)(X + (size_t)(r0 + r) * 768 + c4 * 4);
    int kb = c4 * 4;
    XsT[(kb + 0) * 12 + r] = v.x;
    XsT[(kb + 1) * 12 + r] = v.y;
    XsT[(kb + 2) * 12 + r] = v.z;
    XsT[(kb + 3) * 12 + r] = v.w;
  }
  __syncthreads();
  if (LN) {
    int w = t >> 6, l = t & 63;  // 8 waves, one row each
    float s = 0.f, ss = 0.f;
#pragma unroll
    for (int m = 0; m < 12; ++m) {
      float x = XsT[(l + 64 * m) * 12 + w];
      s += x; ss += x * x;
    }
#pragma unroll
    for (int o = 32; o; o >>= 1) { s += __shfl_xor(s, o); ss += __shfl_xor(ss, o); }
    float mu = s * (1.f / 768.f), rs = rsqrtf(ss * (1.f / 768.f) - mu * mu + LNEPS);
#pragma unroll
    for (int m = 0; m < 12; ++m) {
      int d = l + 64 * m;
      XsT[d * 12 + w] = (XsT[d * 12 + w] - mu) * rs * gamma[d] + beta_ln[d];
    }
    __syncthreads();
  }
  int cx = t & 127, kg = t >> 7;
  int c = c0 + cx;
  float acc[8] = {};
  const float* wp = W + c;
  int k0 = kg * 192;
#pragma unroll 4
  for (int k = k0; k < k0 + 192; ++k) {
    float wv = wp[(size_t)k * 768];
    float4 xa = *(const float4*)&XsT[k * 12];
    float4 xb = *(const float4*)&XsT[k * 12 + 4];
    acc[0] += xa.x * wv; acc[1] += xa.y * wv; acc[2] += xa.z * wv; acc[3] += xa.w * wv;
    acc[4] += xb.x * wv; acc[5] += xb.y * wv; acc[6] += xb.z * wv; acc[7] += xb.w * wv;
  }
  __syncthreads();  // done reading XsT; reuse as reduce buffer
  float* red = XsT;
  if (kg > 0) {
#pragma unroll
    for (int r = 0; r < 8; ++r) red[((kg - 1) * 8 + r) * 128 + cx] = acc[r];
  }
  __syncthreads();
  if (kg == 0) {
#pragma unroll
    for (int g = 1; g < 4; ++g)
#pragma unroll
      for (int r = 0; r < 8; ++r) acc[r] += red[((g - 1) * 8 + r) * 128 + cx];
    float bsc = (MODE == 1) ? 0.f : bias[c];
#pragma unroll
    for (int r = 0; r < 8; ++r) {
      int rr = r0 + r;
      size_t oidx = (size_t)rr * 768 + c;
      float v;
      if (MODE == 0) v = acc[r] + bsc;
      else if (MODE == 1) v = acc[r];
      else if (MODE == 2) v = acc[r] * alpha[rr] + bsc * beta[rr];
      else if (MODE == 3) v = fmaxf(acc[r] + bsc, 0.f);
      else v = out[oidx] + acc[r] + bsc;
      out[oidx] = v;
    }
  }
}

// ---------------- per-slot scalars: Sq = qk.g_in ; c0 = qk.b_in + q.bk ----------------
__global__ void qprep_k(const float* __restrict__ q, const float* __restrict__ qk,
                        const float* __restrict__ g_in, const float* __restrict__ b_in,
                        const float* __restrict__ bk, float* __restrict__ Sqbuf,
                        float* __restrict__ c0buf) {
  int row = blockIdx.x * 4 + (threadIdx.x >> 6), l = threadIdx.x & 63;
  float aS = 0.f, aC = 0.f;
#pragma unroll
  for (int j = 0; j < 12; ++j) {
    int d = l + 64 * j;
    float qkv = qk[(size_t)row * 768 + d];
    aS += qkv * g_in[d];
    aC += qkv * b_in[d] + q[(size_t)row * 768 + d] * bk[d];
  }
#pragma unroll
  for (int o = 32; o; o >>= 1) { aS += __shfl_xor(aS, o); aC += __shfl_xor(aC, o); }
  if (l == 0) { Sqbuf[row] = aS; c0buf[row] = aC; }
}

// ---------------- FUSED dots+softmax+pool over packed-bf16 x ----------------
// grid (16 chunk, 32 b), 512 thr = 8 waves. Phase 1: dots/softmax, 16-lane row groups
// (4 rows per wave-iter, butterfly over 16 lanes only). Phase 2: pool from L2-hot rows
// with w read from LDS; idle lanes compute per-chunk A0/A1 partials.
__global__ void __launch_bounds__(512, 2)
dotspool_k(const uint32* __restrict__ xh, const float* __restrict__ qk,
           const float* __restrict__ g_in, const float* __restrict__ Sqbuf,
           const float* __restrict__ c0buf, float* __restrict__ attnbuf,
           float* __restrict__ partials, float* __restrict__ A0p,
           float* __restrict__ A1p) {
  __shared__ float qkgs[8][768];
  __shared__ float oa[64][8], ow[64][8], orm[64];
  __shared__ float c0s[8], Sqs[8];
  int chunk = blockIdx.x, b = blockIdx.y, t = threadIdx.x, w = t >> 6, l = t & 63;
  for (int i = t; i < 6144; i += 512)
    ((float*)qkgs)[i] = qk[(size_t)b * 6144 + i] * g_in[i % 768];
  if (t < 8) { c0s[t] = c0buf[b * 8 + t]; Sqs[t] = Sqbuf[b * 8 + t]; }
  __syncthreads();
  int g = l & 15, grp = l >> 4;
#pragma unroll
  for (int it = 0; it < 2; ++it) {
    int lr = w * 8 + it * 4 + grp;  // 0..63
    size_t row = (size_t)b * 1024 + chunk * 64 + lr;
    const uint32* xr = xh + row * 384;
    float s = 0.f, ss = 0.f, ds[8] = {};
#pragma unroll 8
    for (int j = 0; j < 24; ++j) {
      uint32 u = xr[j * 16 + g];
      float a = __uint_as_float(u << 16);
      float bv = __uint_as_float(u & 0xffff0000u);
      s += a + bv;
      ss += a * a + bv * bv;
      int d0 = 2 * (j * 16 + g);
#pragma unroll
      for (int s2 = 0; s2 < 8; ++s2) {
        float2 qg = *(const float2*)&qkgs[s2][d0];
        ds[s2] += qg.x * a + qg.y * bv;
      }
    }
#pragma unroll
    for (int o = 1; o < 16; o <<= 1) {
      s += __shfl_xor(s, o);
      ss += __shfl_xor(ss, o);
#pragma unroll
      for (int s2 = 0; s2 < 8; ++s2) ds[s2] += __shfl_xor(ds[s2], o);
    }
    float mu = s * (1.f / 768.f), r = rsqrtf(ss * (1.f / 768.f) - mu * mu + LNEPS);
    float rmu = r * mu;
    float sc[8];
#pragma unroll
    for (int s2 = 0; s2 < 8; ++s2)
      sc[s2] = (r * ds[s2] - rmu * Sqs[s2] + c0s[s2]) * SCALE_Q;
    float mx = sc[0];
#pragma unroll
    for (int s2 = 1; s2 < 8; ++s2) mx = fmaxf(mx, sc[s2]);
    float e[8], se = 0.f;
#pragma unroll
    for (int s2 = 0; s2 < 8; ++s2) { e[s2] = __expf(sc[s2] - mx); se += e[s2]; }
    float inv_se = 1.f / se;
    float av = e[0];
#pragma unroll
    for (int s2 = 1; s2 < 8; ++s2) av = (g == s2) ? e[s2] : av;
    av *= inv_se;
    if (g < 8) {
      oa[lr][g] = av;
      ow[lr][g] = av * r;
    }
    if (g == 8) orm[lr] = rmu;
  }
  __syncthreads();
  // Phase 2: pool (threads 0..383, one packed col each), A-partials (384..391)
  if (t < 384) {
    float acc[8][2] = {};
    const uint32* xp = xh + ((size_t)b * 1024 + chunk * 64) * 384;
#pragma unroll 2
    for (int nn = 0; nn < 64; ++nn) {
      uint32 u = xp[(size_t)nn * 384 + t];
      float x0 = __uint_as_float(u << 16);
      float x1 = __uint_as_float(u & 0xffff0000u);
#pragma unroll
      for (int s2 = 0; s2 < 8; ++s2) {
        float wv = ow[nn][s2];
        acc[s2][0] += wv * x0; acc[s2][1] += wv * x1;
      }
    }
#pragma unroll
    for (int s2 = 0; s2 < 8; ++s2) {
      size_t base = ((size_t)(chunk * 256 + b * 8 + s2)) * 768;
      float2 v; v.x = acc[s2][0]; v.y = acc[s2][1];
      *(float2*)&partials[base + 2 * t] = v;
    }
  } else if (t < 392) {
    int sl = t - 384;
    float A0 = 0.f, A1 = 0.f;
    for (int rr2 = 0; rr2 < 64; ++rr2) {
      float a = oa[rr2][sl];
      A0 += a;
      A1 += a * orm[rr2];
    }
    A0p[chunk * 256 + b * 8 + sl] = A0;
    A1p[chunk * 256 + b * 8 + sl] = A1;
  }
  size_t base8 = ((size_t)b * 1024 + chunk * 64) * 8;
  attnbuf[base8 + t] = oa[t >> 3][t & 7];
}

// ---------------- reduce partials + A0/A1 + LN-fixup -> pooled ; inv, rho ----------------
// grid 256 (row = b*8+s), 256 thr
__global__ void reduce_fix_k(const float* __restrict__ partials, const float* __restrict__ A0p,
                             const float* __restrict__ A1p, const float* __restrict__ g_in,
                             const float* __restrict__ b_in, float* __restrict__ pooled,
                             float* __restrict__ invbuf, float* __restrict__ rhobuf) {
  int row = blockIdx.x, t = threadIdx.x;  // row = b*8+s
  float A0 = 0.f, A1 = 0.f;
#pragma unroll
  for (int ch = 0; ch < 16; ++ch) {
    A0 += A0p[ch * 256 + row];
    A1 += A1p[ch * 256 + row];
  }
#pragma unroll
  for (int c = 0; c < 3; ++c) {
    int d = t + 256 * c;
    float a = 0.f;
    for (int ch = 0; ch < 16; ++ch) a += partials[((size_t)(ch * 256 + row)) * 768 + d];
    pooled[(size_t)row * 768 + d] = g_in[d] * (a - A1) + b_in[d] * A0;
  }
  if (t == 0) {
    float iv = 1.f / (A0 + AEPS);
    invbuf[row] = iv;
    rhobuf[row] = A0 * iv;
  }
}

// ---------------- merged output writer (fp32) ----------------
__global__ void outs_k(const float* __restrict__ slots, const float* __restrict__ attnbuf,
                       const float* __restrict__ invbuf, float* __restrict__ out) {
  int i = blockIdx.x * 256 + threadIdx.x;  // 458752
  if (i < 196608) {
    out[i] = slots[i];
  } else {
    int j = i - 196608;  // [b][n][s]
    out[i] = attnbuf[j] * invbuf[((j >> 13) << 3) + (j & 7)];
  }
}

extern "C" void kernel_launch(void* const* d_in, const int* in_sizes, int n_in,
                              void* d_out, int out_size, void* d_ws, size_t ws_size,
                              hipStream_t stream) {
  (void)in_sizes; (void)n_in; (void)out_size; (void)ws_size;
  const float* slots0 = (const float*)d_in[0];
  const float* inputs = (const float*)d_in[1];
  const float* Wq = (const float*)d_in[2];
  const float* bq = (const float*)d_in[3];
  const float* Wk = (const float*)d_in[4];
  const float* bk = (const float*)d_in[5];
  const float* Wv = (const float*)d_in[6];
  const float* bv = (const float*)d_in[7];
  const float* g_in = (const float*)d_in[8];
  const float* b_in = (const float*)d_in[9];
  const float* g_s = (const float*)d_in[10];
  const float* b_s = (const float*)d_in[11];
  const float* g_ff = (const float*)d_in[12];
  const float* b_ff = (const float*)d_in[13];
  const float* W1 = (const float*)d_in[14];
  const float* b1 = (const float*)d_in[15];
  const float* W2 = (const float*)d_in[16];
  const float* b2 = (const float*)d_in[17];

  char* p = (char*)d_ws;
  uint32* xh = (uint32*)p;     p += (size_t)32768 * 384 * 4;  // packed bf16 inputs
  float* WkT = (float*)p;      p += (size_t)768 * 768 * 4;
  float* slotsf = (float*)p;   p += 256 * 768 * 4;
  float* qbuf = (float*)p;     p += 256 * 768 * 4;
  float* qkbuf = (float*)p;    p += 256 * 768 * 4;
  float* Sqbuf = (float*)p;    p += 256 * 4;
  float* c0buf = (float*)p;    p += 256 * 4;
  float* attnbuf = (float*)p;  p += (size_t)32768 * 8 * 4;
  float* partials = (float*)p; p += (size_t)16 * 256 * 768 * 4;
  float* A0p = (float*)p;      p += 16 * 256 * 4;
  float* A1p = (float*)p;      p += 16 * 256 * 4;
  float* pooled = (float*)p;   p += 256 * 768 * 4;
  float* invbuf = (float*)p;   p += 256 * 4;
  float* rhobuf = (float*)p;   p += 256 * 4;
  float* updbuf = (float*)p;   p += 256 * 768 * 4;
  float* t1buf = (float*)p;    p += 256 * 768 * 4;

  dim3 ggrid(6, 32);
  cast_k<<<24576, 256, 0, stream>>>(inputs, xh);
  packT_k<<<dim3(24, 24), 256, 0, stream>>>(Wk, WkT);
  init_slots_k<<<768, 256, 0, stream>>>(slots0, slotsf);
  for (int it = 0; it < 3; ++it) {
    gemv_k<true, 0><<<ggrid, 512, 0, stream>>>(slotsf, Wq, bq, g_s, b_s, nullptr, nullptr,
                                               qbuf);
    gemv_k<false, 1><<<ggrid, 512, 0, stream>>>(qbuf, WkT, nullptr, nullptr, nullptr, nullptr,
                                                nullptr, qkbuf);
    qprep_k<<<64, 256, 0, stream>>>(qbuf, qkbuf, g_in, b_in, bk, Sqbuf, c0buf);
    dotspool_k<<<dim3(16, 32), 512, 0, stream>>>(xh, qkbuf, g_in, Sqbuf, c0buf, attnbuf,
                                                 partials, A0p, A1p);
    reduce_fix_k<<<256, 256, 0, stream>>>(partials, A0p, A1p, g_in, b_in, pooled,
                                          invbuf, rhobuf);
    gemv_k<false, 2><<<ggrid, 512, 0, stream>>>(pooled, Wv, bv, nullptr, nullptr, invbuf,
                                                rhobuf, updbuf);
    gemv_k<true, 3><<<ggrid, 512, 0, stream>>>(updbuf, W1, b1, g_ff, b_ff, nullptr, nullptr,
                                               t1buf);
    gemv_k<false, 4><<<ggrid, 512, 0, stream>>>(t1buf, W2, b2, nullptr, nullptr, nullptr,
                                                nullptr, slotsf);
  }
  outs_k<<<1792, 256, 0, stream>>>(slotsf, attnbuf, invbuf, (float*)d_out);
}

// Round 15
// 467.683 us; speedup vs baseline: 1.2225x; 1.0390x over previous
//
#include <hip/hip_runtime.h>

#define LNEPS 1e-5f
#define AEPS 1e-8f
#define SCALE_Q 0.036084391824351615f  // 768^-0.5

typedef unsigned int uint32;

__device__ inline unsigned short bfb(float f) {
  __bf16 h = (__bf16)f;
  unsigned short u;
  __builtin_memcpy(&u, &h, 2);
  return u;
}

// ---------------- merged one-time setup: cast | packT | init_slots ----------------
// blocks [0,24576): cast fp32->packed bf16 ; [24576,25152): transpose Wk ; [25152,25920): init slots
__global__ void setup_k(const float* __restrict__ in, uint32* __restrict__ xh,
                        const float* __restrict__ Wk, float* __restrict__ WkT,
                        const float* __restrict__ s0, float* __restrict__ slots) {
  __shared__ float tile[32][33];
  int bb = blockIdx.x, t = threadIdx.x;
  if (bb < 24576) {
    size_t i = (size_t)bb * 256 + t;  // 6291456 float4s
    float4 v = ((const float4*)in)[i];
    uint2 o;
    o.x = (uint32)bfb(v.x) | ((uint32)bfb(v.y) << 16);
    o.y = (uint32)bfb(v.z) | ((uint32)bfb(v.w) << 16);
    ((uint2*)xh)[i] = o;
  } else if (bb < 25152) {
    int pb = bb - 24576;
    int c0 = (pb % 24) * 32, i0 = (pb / 24) * 32;
    int tx = t & 31, ty = t >> 5;
#pragma unroll
    for (int k = 0; k < 4; ++k)
      tile[ty + 8 * k][tx] = Wk[(size_t)(i0 + ty + 8 * k) * 768 + c0 + tx];
    __syncthreads();
#pragma unroll
    for (int k = 0; k < 4; ++k)
      WkT[(size_t)(c0 + ty + 8 * k) * 768 + i0 + tx] = tile[tx][ty + 8 * k];
  } else {
    int idx = (bb - 25152) * 256 + t;  // 196608
    slots[idx] = s0[idx % 6144];
  }
}

// ---------------- batched GEMV v2: coalesced col-per-thread, 512 thr, grid (6,32) --------
// MODE 0: acc+bias | 1: acc | 2: alpha[r]*acc+beta[r]*bias | 3: relu(acc+bias) | 4: out+=acc+bias
template <bool LN, int MODE>
__global__ void gemv_k(const float* __restrict__ X, const float* __restrict__ W,
                       const float* __restrict__ bias, const float* __restrict__ gamma,
                       const float* __restrict__ beta_ln, const float* __restrict__ alpha,
                       const float* __restrict__ beta, float* __restrict__ out) {
  __shared__ float XsT[768 * 12];  // [k][r] stride 12
  int t = threadIdx.x;
  int c0 = blockIdx.x * 128, r0 = blockIdx.y * 8;
#pragma unroll
  for (int j = 0; j < 3; ++j) {
    int fidx = j * 512 + t;  // 0..1535
    int r = fidx / 192, c4 = fidx % 192;
    float4 v = *(const float4*)(X + (size_t)(r0 + r) * 768 + c4 * 4);
    int kb = c4 * 4;
    XsT[(kb + 0) * 12 + r] = v.x;
    XsT[(kb + 1) * 12 + r] = v.y;
    XsT[(kb + 2) * 12 + r] = v.z;
    XsT[(kb + 3) * 12 + r] = v.w;
  }
  __syncthreads();
  if (LN) {
    int w = t >> 6, l = t & 63;  // 8 waves, one row each
    float s = 0.f, ss = 0.f;
#pragma unroll
    for (int m = 0; m < 12; ++m) {
      float x = XsT[(l + 64 * m) * 12 + w];
      s += x; ss += x * x;
    }
#pragma unroll
    for (int o = 32; o; o >>= 1) { s += __shfl_xor(s, o); ss += __shfl_xor(ss, o); }
    float mu = s * (1.f / 768.f), rs = rsqrtf(ss * (1.f / 768.f) - mu * mu + LNEPS);
#pragma unroll
    for (int m = 0; m < 12; ++m) {
      int d = l + 64 * m;
      XsT[d * 12 + w] = (XsT[d * 12 + w] - mu) * rs * gamma[d] + beta_ln[d];
    }
    __syncthreads();
  }
  int cx = t & 127, kg = t >> 7;
  int c = c0 + cx;
  float acc[8] = {};
  const float* wp = W + c;
  int k0 = kg * 192;
#pragma unroll 4
  for (int k = k0; k < k0 + 192; ++k) {
    float wv = wp[(size_t)k * 768];
    float4 xa = *(const float4*)&XsT[k * 12];
    float4 xb = *(const float4*)&XsT[k * 12 + 4];
    acc[0] += xa.x * wv; acc[1] += xa.y * wv; acc[2] += xa.z * wv; acc[3] += xa.w * wv;
    acc[4] += xb.x * wv; acc[5] += xb.y * wv; acc[6] += xb.z * wv; acc[7] += xb.w * wv;
  }
  __syncthreads();  // done reading XsT; reuse as reduce buffer
  float* red = XsT;
  if (kg > 0) {
#pragma unroll
    for (int r = 0; r < 8; ++r) red[((kg - 1) * 8 + r) * 128 + cx] = acc[r];
  }
  __syncthreads();
  if (kg == 0) {
#pragma unroll
    for (int g = 1; g < 4; ++g)
#pragma unroll
      for (int r = 0; r < 8; ++r) acc[r] += red[((g - 1) * 8 + r) * 128 + cx];
    float bsc = (MODE == 1) ? 0.f : bias[c];
#pragma unroll
    for (int r = 0; r < 8; ++r) {
      int rr = r0 + r;
      size_t oidx = (size_t)rr * 768 + c;
      float v;
      if (MODE == 0) v = acc[r] + bsc;
      else if (MODE == 1) v = acc[r];
      else if (MODE == 2) v = acc[r] * alpha[rr] + bsc * beta[rr];
      else if (MODE == 3) v = fmaxf(acc[r] + bsc, 0.f);
      else v = out[oidx] + acc[r] + bsc;
      out[oidx] = v;
    }
  }
}

// ---------------- per-slot scalars: Sq = qk.g_in ; c0 = qk.b_in + q.bk ----------------
__global__ void qprep_k(const float* __restrict__ q, const float* __restrict__ qk,
                        const float* __restrict__ g_in, const float* __restrict__ b_in,
                        const float* __restrict__ bk, float* __restrict__ Sqbuf,
                        float* __restrict__ c0buf) {
  int row = blockIdx.x * 4 + (threadIdx.x >> 6), l = threadIdx.x & 63;
  float aS = 0.f, aC = 0.f;
#pragma unroll
  for (int j = 0; j < 12; ++j) {
    int d = l + 64 * j;
    float qkv = qk[(size_t)row * 768 + d];
    aS += qkv * g_in[d];
    aC += qkv * b_in[d] + q[(size_t)row * 768 + d] * bk[d];
  }
#pragma unroll
  for (int o = 32; o; o >>= 1) { aS += __shfl_xor(aS, o); aC += __shfl_xor(aC, o); }
  if (l == 0) { Sqbuf[row] = aS; c0buf[row] = aC; }
}

// ---------------- FUSED dots+softmax+pool, x staged in LDS (2 subtiles x 32 rows) -------
// grid (16 chunk, 32 b), 512 thr = 8 waves. Per subtile: stage -> dots (16-lane groups,
// 4 rows/wave) -> pool from LDS. Global x read ONCE per chunk.
__global__ void __launch_bounds__(512, 2)
dotspool_k(const uint32* __restrict__ xh, const float* __restrict__ qk,
           const float* __restrict__ g_in, const float* __restrict__ Sqbuf,
           const float* __restrict__ c0buf, float* __restrict__ attnbuf,
           float* __restrict__ partials, float* __restrict__ A0p,
           float* __restrict__ A1p) {
  __shared__ float qkgs[8][768];
  __shared__ uint32 xt[32 * 392];  // 32 rows x 384 packed cols, stride 392 (bank +8/row)
  __shared__ float oa[64][8], ow[64][8], orm[64];
  __shared__ float c0s[8], Sqs[8];
  int chunk = blockIdx.x, b = blockIdx.y, t = threadIdx.x, w = t >> 6, l = t & 63;
  for (int i = t; i < 6144; i += 512)
    ((float*)qkgs)[i] = qk[(size_t)b * 6144 + i] * g_in[i % 768];
  if (t < 8) { c0s[t] = c0buf[b * 8 + t]; Sqs[t] = Sqbuf[b * 8 + t]; }
  int g = l & 15, grp = l >> 4;
  const uint32* xp = xh + ((size_t)b * 1024 + chunk * 64) * 384;
  float pacc[8][2] = {};
#pragma unroll
  for (int sub = 0; sub < 2; ++sub) {
    // stage 32 rows (12288 uints) coalesced
#pragma unroll
    for (int j = 0; j < 24; ++j) {
      int idx = j * 512 + t;
      xt[(idx / 384) * 392 + (idx % 384)] = xp[sub * 12288 + idx];
    }
    __syncthreads();
    // dots+softmax: 8 waves x 4 groups = 32 rows
    {
      int lr32 = w * 4 + grp;
      int lr = sub * 32 + lr32;
      const uint32* xr = &xt[lr32 * 392];
      float s = 0.f, ss = 0.f, ds[8] = {};
#pragma unroll 8
      for (int j = 0; j < 24; ++j) {
        uint32 u = xr[j * 16 + g];
        float a = __uint_as_float(u << 16);
        float bv = __uint_as_float(u & 0xffff0000u);
        s += a + bv;
        ss += a * a + bv * bv;
        int d0 = 2 * (j * 16 + g);
#pragma unroll
        for (int s2 = 0; s2 < 8; ++s2) {
          float2 qg = *(const float2*)&qkgs[s2][d0];
          ds[s2] += qg.x * a + qg.y * bv;
        }
      }
#pragma unroll
      for (int o = 1; o < 16; o <<= 1) {
        s += __shfl_xor(s, o);
        ss += __shfl_xor(ss, o);
#pragma unroll
        for (int s2 = 0; s2 < 8; ++s2) ds[s2] += __shfl_xor(ds[s2], o);
      }
      float mu = s * (1.f / 768.f), r = rsqrtf(ss * (1.f / 768.f) - mu * mu + LNEPS);
      float rmu = r * mu;
      float sc[8];
#pragma unroll
      for (int s2 = 0; s2 < 8; ++s2)
        sc[s2] = (r * ds[s2] - rmu * Sqs[s2] + c0s[s2]) * SCALE_Q;
      float mx = sc[0];
#pragma unroll
      for (int s2 = 1; s2 < 8; ++s2) mx = fmaxf(mx, sc[s2]);
      float e[8], se = 0.f;
#pragma unroll
      for (int s2 = 0; s2 < 8; ++s2) { e[s2] = __expf(sc[s2] - mx); se += e[s2]; }
      float inv_se = 1.f / se;
      float av = e[0];
#pragma unroll
      for (int s2 = 1; s2 < 8; ++s2) av = (g == s2) ? e[s2] : av;
      av *= inv_se;
      if (g < 8) {
        oa[lr][g] = av;
        ow[lr][g] = av * r;
      }
      if (g == 8) orm[lr] = rmu;
    }
    __syncthreads();
    // pool this subtile from LDS (threads 0..383 own one packed col)
    if (t < 384) {
#pragma unroll 2
      for (int nn = 0; nn < 32; ++nn) {
        uint32 u = xt[nn * 392 + t];
        float x0 = __uint_as_float(u << 16);
        float x1 = __uint_as_float(u & 0xffff0000u);
#pragma unroll
        for (int s2 = 0; s2 < 8; ++s2) {
          float wv = ow[sub * 32 + nn][s2];
          pacc[s2][0] += wv * x0; pacc[s2][1] += wv * x1;
        }
      }
    } else if (sub == 1 && t < 392) {
      int sl = t - 384;
      float A0 = 0.f, A1 = 0.f;
      for (int rr2 = 0; rr2 < 64; ++rr2) {
        float a = oa[rr2][sl];
        A0 += a;
        A1 += a * orm[rr2];
      }
      A0p[chunk * 256 + b * 8 + sl] = A0;
      A1p[chunk * 256 + b * 8 + sl] = A1;
    }
    __syncthreads();
  }
  if (t < 384) {
#pragma unroll
    for (int s2 = 0; s2 < 8; ++s2) {
      size_t base = ((size_t)(chunk * 256 + b * 8 + s2)) * 768;
      float2 v; v.x = pacc[s2][0]; v.y = pacc[s2][1];
      *(float2*)&partials[base + 2 * t] = v;
    }
  }
  size_t base8 = ((size_t)b * 1024 + chunk * 64) * 8;
  attnbuf[base8 + t] = oa[t >> 3][t & 7];
}

// ---------------- reduce partials + A0/A1 + LN-fixup -> pooled ; inv, rho ----------------
// grid 256 (row = b*8+s), 256 thr
__global__ void reduce_fix_k(const float* __restrict__ partials, const float* __restrict__ A0p,
                             const float* __restrict__ A1p, const float* __restrict__ g_in,
                             const float* __restrict__ b_in, float* __restrict__ pooled,
                             float* __restrict__ invbuf, float* __restrict__ rhobuf) {
  int row = blockIdx.x, t = threadIdx.x;  // row = b*8+s
  float A0 = 0.f, A1 = 0.f;
#pragma unroll
  for (int ch = 0; ch < 16; ++ch) {
    A0 += A0p[ch * 256 + row];
    A1 += A1p[ch * 256 + row];
  }
#pragma unroll
  for (int c = 0; c < 3; ++c) {
    int d = t + 256 * c;
    float a = 0.f;
    for (int ch = 0; ch < 16; ++ch) a += partials[((size_t)(ch * 256 + row)) * 768 + d];
    pooled[(size_t)row * 768 + d] = g_in[d] * (a - A1) + b_in[d] * A0;
  }
  if (t == 0) {
    float iv = 1.f / (A0 + AEPS);
    invbuf[row] = iv;
    rhobuf[row] = A0 * iv;
  }
}

// ---------------- merged output writer (fp32) ----------------
__global__ void outs_k(const float* __restrict__ slots, const float* __restrict__ attnbuf,
                       const float* __restrict__ invbuf, float* __restrict__ out) {
  int i = blockIdx.x * 256 + threadIdx.x;  // 458752
  if (i < 196608) {
    out[i] = slots[i];
  } else {
    int j = i - 196608;  // [b][n][s]
    out[i] = attnbuf[j] * invbuf[((j >> 13) << 3) + (j & 7)];
  }
}

extern "C" void kernel_launch(void* const* d_in, const int* in_sizes, int n_in,
                              void* d_out, int out_size, void* d_ws, size_t ws_size,
                              hipStream_t stream) {
  (void)in_sizes; (void)n_in; (void)out_size; (void)ws_size;
  const float* slots0 = (const float*)d_in[0];
  const float* inputs = (const float*)d_in[1];
  const float* Wq = (const float*)d_in[2];
  const float* bq = (const float*)d_in[3];
  const float* Wk = (const float*)d_in[4];
  const float* bk = (const float*)d_in[5];
  const float* Wv = (const float*)d_in[6];
  const float* bv = (const float*)d_in[7];
  const float* g_in = (const float*)d_in[8];
  const float* b_in = (const float*)d_in[9];
  const float* g_s = (const float*)d_in[10];
  const float* b_s = (const float*)d_in[11];
  const float* g_ff = (const float*)d_in[12];
  const float* b_ff = (const float*)d_in[13];
  const float* W1 = (const float*)d_in[14];
  const float* b1 = (const float*)d_in[15];
  const float* W2 = (const float*)d_in[16];
  const float* b2 = (const float*)d_in[17];

  char* p = (char*)d_ws;
  uint32* xh = (uint32*)p;     p += (size_t)32768 * 384 * 4;  // packed bf16 inputs
  float* WkT = (float*)p;      p += (size_t)768 * 768 * 4;
  float* slotsf = (float*)p;   p += 256 * 768 * 4;
  float* qbuf = (float*)p;     p += 256 * 768 * 4;
  float* qkbuf = (float*)p;    p += 256 * 768 * 4;
  float* Sqbuf = (float*)p;    p += 256 * 4;
  float* c0buf = (float*)p;    p += 256 * 4;
  float* attnbuf = (float*)p;  p += (size_t)32768 * 8 * 4;
  float* partials = (float*)p; p += (size_t)16 * 256 * 768 * 4;
  float* A0p = (float*)p;      p += 16 * 256 * 4;
  float* A1p = (float*)p;      p += 16 * 256 * 4;
  float* pooled = (float*)p;   p += 256 * 768 * 4;
  float* invbuf = (float*)p;   p += 256 * 4;
  float* rhobuf = (float*)p;   p += 256 * 4;
  float* updbuf = (float*)p;   p += 256 * 768 * 4;
  float* t1buf = (float*)p;    p += 256 * 768 * 4;

  dim3 ggrid(6, 32);
  setup_k<<<25920, 256, 0, stream>>>(inputs, xh, Wk, WkT, slots0, slotsf);
  for (int it = 0; it < 3; ++it) {
    gemv_k<true, 0><<<ggrid, 512, 0, stream>>>(slotsf, Wq, bq, g_s, b_s, nullptr, nullptr,
                                               qbuf);
    gemv_k<false, 1><<<ggrid, 512, 0, stream>>>(qbuf, WkT, nullptr, nullptr, nullptr, nullptr,
                                                nullptr, qkbuf);
    qprep_k<<<64, 256, 0, stream>>>(qbuf, qkbuf, g_in, b_in, bk, Sqbuf, c0buf);
    dotspool_k<<<dim3(16, 32), 512, 0, stream>>>(xh, qkbuf, g_in, Sqbuf, c0buf, attnbuf,
                                                 partials, A0p, A1p);
    reduce_fix_k<<<256, 256, 0, stream>>>(partials, A0p, A1p, g_in, b_in, pooled,
                                          invbuf, rhobuf);
    gemv_k<false, 2><<<ggrid, 512, 0, stream>>>(pooled, Wv, bv, nullptr, nullptr, invbuf,
                                                rhobuf, updbuf);
    gemv_k<true, 3><<<ggrid, 512, 0, stream>>>(updbuf, W1, b1, g_ff, b_ff, nullptr, nullptr,
                                               t1buf);
    gemv_k<false, 4><<<ggrid, 512, 0, stream>>>(t1buf, W2, b2, nullptr, nullptr, nullptr,
                                                nullptr, slotsf);
  }
  outs_k<<<1792, 256, 0, stream>>>(slotsf, attnbuf, invbuf, (float*)d_out);
}

// Round 16
// 343.730 us; speedup vs baseline: 1.6634x; 1.3606x over previous
//
#include <hip/hip_runtime.h>

#define LNEPS 1e-5f
#define AEPS 1e-8f
#define SCALE_Q 0.036084391824351615f  // 768^-0.5

typedef unsigned int uint32;

__device__ inline uint32 bfb(float f) {
  __bf16 h = (__bf16)f;
  unsigned short u;
  __builtin_memcpy(&u, &h, 2);
  return (uint32)u;
}

// ---------------- one-time setup: packT Wk | init slots ----------------
// blocks [0,576): transpose Wk ; [576,1344): init slots
__global__ void setup_k(const float* __restrict__ Wk, float* __restrict__ WkT,
                        const float* __restrict__ s0, float* __restrict__ slots) {
  __shared__ float tile[32][33];
  int bb = blockIdx.x, t = threadIdx.x;
  if (bb < 576) {
    int c0 = (bb % 24) * 32, i0 = (bb / 24) * 32;
    int tx = t & 31, ty = t >> 5;
#pragma unroll
    for (int k = 0; k < 4; ++k)
      tile[ty + 8 * k][tx] = Wk[(size_t)(i0 + ty + 8 * k) * 768 + c0 + tx];
    __syncthreads();
#pragma unroll
    for (int k = 0; k < 4; ++k)
      WkT[(size_t)(c0 + ty + 8 * k) * 768 + i0 + tx] = tile[tx][ty + 8 * k];
  } else {
    int idx = (bb - 576) * 256 + t;  // 196608
    slots[idx] = s0[idx % 6144];
  }
}

// ---------------- batched GEMV v3: 64 cols/block, 8-way k-split, 512 thr, grid (12,32) ----
// Thread: c = bx*64 + (t&63); kg = t>>6 (k in [kg*96, +96)); rows r0 = by*8..+8.
// MODE 0: acc+bias | 1: acc | 2: alpha[r]*acc+beta[r]*bias | 3: relu(acc+bias) | 4: out+=acc+bias
template <bool LN, int MODE>
__global__ void gemv_k(const float* __restrict__ X, const float* __restrict__ W,
                       const float* __restrict__ bias, const float* __restrict__ gamma,
                       const float* __restrict__ beta_ln, const float* __restrict__ alpha,
                       const float* __restrict__ beta, float* __restrict__ out) {
  __shared__ float XsT[768 * 12];  // [k][r] stride 12
  int t = threadIdx.x;
  int c0 = blockIdx.x * 64, r0 = blockIdx.y * 8;
#pragma unroll
  for (int j = 0; j < 3; ++j) {
    int fidx = j * 512 + t;  // 0..1535
    int r = fidx / 192, c4 = fidx % 192;
    float4 v = *(const float4*)(X + (size_t)(r0 + r) * 768 + c4 * 4);
    int kb = c4 * 4;
    XsT[(kb + 0) * 12 + r] = v.x;
    XsT[(kb + 1) * 12 + r] = v.y;
    XsT[(kb + 2) * 12 + r] = v.z;
    XsT[(kb + 3) * 12 + r] = v.w;
  }
  __syncthreads();
  if (LN) {
    int w = t >> 6, l = t & 63;  // 8 waves, one row each
    float s = 0.f, ss = 0.f;
#pragma unroll
    for (int m = 0; m < 12; ++m) {
      float x = XsT[(l + 64 * m) * 12 + w];
      s += x; ss += x * x;
    }
#pragma unroll
    for (int o = 32; o; o >>= 1) { s += __shfl_xor(s, o); ss += __shfl_xor(ss, o); }
    float mu = s * (1.f / 768.f), rs = rsqrtf(ss * (1.f / 768.f) - mu * mu + LNEPS);
#pragma unroll
    for (int m = 0; m < 12; ++m) {
      int d = l + 64 * m;
      XsT[d * 12 + w] = (XsT[d * 12 + w] - mu) * rs * gamma[d] + beta_ln[d];
    }
    __syncthreads();
  }
  int cx = t & 63, kg = t >> 6;
  int c = c0 + cx;
  float acc[8] = {};
  const float* wp = W + c;
  int k0 = kg * 96;
#pragma unroll 8
  for (int k = k0; k < k0 + 96; ++k) {
    float wv = wp[(size_t)k * 768];
    float4 xa = *(const float4*)&XsT[k * 12];
    float4 xb = *(const float4*)&XsT[k * 12 + 4];
    acc[0] += xa.x * wv; acc[1] += xa.y * wv; acc[2] += xa.z * wv; acc[3] += xa.w * wv;
    acc[4] += xb.x * wv; acc[5] += xb.y * wv; acc[6] += xb.z * wv; acc[7] += xb.w * wv;
  }
  __syncthreads();  // done reading XsT; reuse as reduce buffer (7*8*64 = 3584 floats)
  float* red = XsT;
  if (kg > 0) {
#pragma unroll
    for (int r = 0; r < 8; ++r) red[((kg - 1) * 8 + r) * 64 + cx] = acc[r];
  }
  __syncthreads();
  if (kg == 0) {
#pragma unroll
    for (int g = 1; g < 8; ++g)
#pragma unroll
      for (int r = 0; r < 8; ++r) acc[r] += red[((g - 1) * 8 + r) * 64 + cx];
    float bsc = (MODE == 1) ? 0.f : bias[c];
#pragma unroll
    for (int r = 0; r < 8; ++r) {
      int rr = r0 + r;
      size_t oidx = (size_t)rr * 768 + c;
      float v;
      if (MODE == 0) v = acc[r] + bsc;
      else if (MODE == 1) v = acc[r];
      else if (MODE == 2) v = acc[r] * alpha[rr] + bsc * beta[rr];
      else if (MODE == 3) v = fmaxf(acc[r] + bsc, 0.f);
      else v = out[oidx] + acc[r] + bsc;
      out[oidx] = v;
    }
  }
}

// ---------------- per-slot scalars: Sq = qk.g_in ; c0 = qk.b_in + q.bk ----------------
__global__ void qprep_k(const float* __restrict__ q, const float* __restrict__ qk,
                        const float* __restrict__ g_in, const float* __restrict__ b_in,
                        const float* __restrict__ bk, float* __restrict__ Sqbuf,
                        float* __restrict__ c0buf) {
  int row = blockIdx.x * 4 + (threadIdx.x >> 6), l = threadIdx.x & 63;
  float aS = 0.f, aC = 0.f;
#pragma unroll
  for (int j = 0; j < 12; ++j) {
    int d = l + 64 * j;
    float qkv = qk[(size_t)row * 768 + d];
    aS += qkv * g_in[d];
    aC += qkv * b_in[d] + q[(size_t)row * 768 + d] * bk[d];
  }
#pragma unroll
  for (int o = 32; o; o >>= 1) { aS += __shfl_xor(aS, o); aC += __shfl_xor(aC, o); }
  if (l == 0) { Sqbuf[row] = aS; c0buf[row] = aC; }
}

// ---------------- FUSED dots+softmax+pool, x staged in LDS (2 subtiles x 32 rows) -------
// grid (16 chunk, 32 b), 512 thr. FIRST: stage from fp32, convert to bf16 in LDS, also
// write packed xh for later iterations (folds the cast pass into iter 0).
// xt stride 390: 4-row group spacing 1560 % 32 = 24 -> <=2-way banks on dots reads (free).
template <bool FIRST>
__global__ void __launch_bounds__(512, 2)
dotspool_k(const float* __restrict__ inf, uint32* __restrict__ xh,
           const float* __restrict__ qk, const float* __restrict__ g_in,
           const float* __restrict__ Sqbuf, const float* __restrict__ c0buf,
           float* __restrict__ attnbuf, float* __restrict__ partials,
           float* __restrict__ A0p, float* __restrict__ A1p) {
  __shared__ float qkgs[8][768];
  __shared__ uint32 xt[32 * 390];
  __shared__ float oa[64][8], ow[64][8], orm[64];
  __shared__ float c0s[8], Sqs[8];
  int chunk = blockIdx.x, b = blockIdx.y, t = threadIdx.x, w = t >> 6, l = t & 63;
  for (int i = t; i < 6144; i += 512)
    ((float*)qkgs)[i] = qk[(size_t)b * 6144 + i] * g_in[i % 768];
  if (t < 8) { c0s[t] = c0buf[b * 8 + t]; Sqs[t] = Sqbuf[b * 8 + t]; }
  int g = l & 15, grp = l >> 4;
  float pacc[8][2] = {};
#pragma unroll
  for (int sub = 0; sub < 2; ++sub) {
    if (FIRST) {
      const float4* xpf =
          (const float4*)(inf + ((size_t)b * 1024 + chunk * 64 + sub * 32) * 768);
      uint2* xg = (uint2*)(xh + ((size_t)b * 1024 + chunk * 64 + sub * 32) * 384);
#pragma unroll
      for (int j = 0; j < 12; ++j) {
        int idx = j * 512 + t;  // 6144 float4s
        int row = idx / 192, c4 = idx % 192;
        float4 v = xpf[(size_t)row * 192 + c4];
        uint2 o;
        o.x = bfb(v.x) | (bfb(v.y) << 16);
        o.y = bfb(v.z) | (bfb(v.w) << 16);
        xt[row * 390 + c4 * 2] = o.x;
        xt[row * 390 + c4 * 2 + 1] = o.y;
        xg[(size_t)row * 192 + c4] = o;
      }
    } else {
      const uint32* xps = xh + ((size_t)b * 1024 + chunk * 64) * 384 + sub * 12288;
#pragma unroll
      for (int j = 0; j < 24; ++j) {
        int idx = j * 512 + t;
        xt[(idx / 384) * 390 + (idx % 384)] = xps[idx];
      }
    }
    __syncthreads();
    // dots+softmax: 8 waves x 4 groups = 32 rows
    {
      int lr32 = w * 4 + grp;
      int lr = sub * 32 + lr32;
      size_t row = (size_t)b * 1024 + chunk * 64 + lr;
      const uint32* xr = &xt[lr32 * 390];
      float s = 0.f, ss = 0.f, ds[8] = {};
#pragma unroll 8
      for (int j = 0; j < 24; ++j) {
        uint32 u = xr[j * 16 + g];
        float a = __uint_as_float(u << 16);
        float bv = __uint_as_float(u & 0xffff0000u);
        s += a + bv;
        ss += a * a + bv * bv;
        int d0 = 2 * (j * 16 + g);
#pragma unroll
        for (int s2 = 0; s2 < 8; ++s2) {
          float2 qg = *(const float2*)&qkgs[s2][d0];
          ds[s2] += qg.x * a + qg.y * bv;
        }
      }
#pragma unroll
      for (int o = 1; o < 16; o <<= 1) {
        s += __shfl_xor(s, o);
        ss += __shfl_xor(ss, o);
#pragma unroll
        for (int s2 = 0; s2 < 8; ++s2) ds[s2] += __shfl_xor(ds[s2], o);
      }
      float mu = s * (1.f / 768.f), r = rsqrtf(ss * (1.f / 768.f) - mu * mu + LNEPS);
      float rmu = r * mu;
      float sc[8];
#pragma unroll
      for (int s2 = 0; s2 < 8; ++s2)
        sc[s2] = (r * ds[s2] - rmu * Sqs[s2] + c0s[s2]) * SCALE_Q;
      float mx = sc[0];
#pragma unroll
      for (int s2 = 1; s2 < 8; ++s2) mx = fmaxf(mx, sc[s2]);
      float e[8], se = 0.f;
#pragma unroll
      for (int s2 = 0; s2 < 8; ++s2) { e[s2] = __expf(sc[s2] - mx); se += e[s2]; }
      float inv_se = 1.f / se;
      float av = e[0];
#pragma unroll
      for (int s2 = 1; s2 < 8; ++s2) av = (g == s2) ? e[s2] : av;
      av *= inv_se;
      if (g < 8) {
        oa[lr][g] = av;
        ow[lr][g] = av * r;
      }
      if (g == 8) orm[lr] = rmu;
      (void)row;
    }
    __syncthreads();
    // pool this subtile from LDS (threads 0..383 own one packed col)
    if (t < 384) {
#pragma unroll 2
      for (int nn = 0; nn < 32; ++nn) {
        uint32 u = xt[nn * 390 + t];
        float x0 = __uint_as_float(u << 16);
        float x1 = __uint_as_float(u & 0xffff0000u);
#pragma unroll
        for (int s2 = 0; s2 < 8; ++s2) {
          float wv = ow[sub * 32 + nn][s2];
          pacc[s2][0] += wv * x0; pacc[s2][1] += wv * x1;
        }
      }
    } else if (sub == 1 && t < 392) {
      int sl = t - 384;
      float A0 = 0.f, A1 = 0.f;
      for (int rr2 = 0; rr2 < 64; ++rr2) {
        float a = oa[rr2][sl];
        A0 += a;
        A1 += a * orm[rr2];
      }
      A0p[chunk * 256 + b * 8 + sl] = A0;
      A1p[chunk * 256 + b * 8 + sl] = A1;
    }
    __syncthreads();
  }
  if (t < 384) {
#pragma unroll
    for (int s2 = 0; s2 < 8; ++s2) {
      size_t base = ((size_t)(chunk * 256 + b * 8 + s2)) * 768;
      float2 v; v.x = pacc[s2][0]; v.y = pacc[s2][1];
      *(float2*)&partials[base + 2 * t] = v;
    }
  }
  size_t base8 = ((size_t)b * 1024 + chunk * 64) * 8;
  attnbuf[base8 + t] = oa[t >> 3][t & 7];
}

// ---------------- reduce partials + A0/A1 + LN-fixup -> pooled ; inv, rho ----------------
// grid 256 (row = b*8+s), 256 thr
__global__ void reduce_fix_k(const float* __restrict__ partials, const float* __restrict__ A0p,
                             const float* __restrict__ A1p, const float* __restrict__ g_in,
                             const float* __restrict__ b_in, float* __restrict__ pooled,
                             float* __restrict__ invbuf, float* __restrict__ rhobuf) {
  int row = blockIdx.x, t = threadIdx.x;  // row = b*8+s
  float A0 = 0.f, A1 = 0.f;
#pragma unroll
  for (int ch = 0; ch < 16; ++ch) {
    A0 += A0p[ch * 256 + row];
    A1 += A1p[ch * 256 + row];
  }
#pragma unroll
  for (int c = 0; c < 3; ++c) {
    int d = t + 256 * c;
    float a = 0.f;
    for (int ch = 0; ch < 16; ++ch) a += partials[((size_t)(ch * 256 + row)) * 768 + d];
    pooled[(size_t)row * 768 + d] = g_in[d] * (a - A1) + b_in[d] * A0;
  }
  if (t == 0) {
    float iv = 1.f / (A0 + AEPS);
    invbuf[row] = iv;
    rhobuf[row] = A0 * iv;
  }
}

// ---------------- merged output writer (fp32) ----------------
__global__ void outs_k(const float* __restrict__ slots, const float* __restrict__ attnbuf,
                       const float* __restrict__ invbuf, float* __restrict__ out) {
  int i = blockIdx.x * 256 + threadIdx.x;  // 458752
  if (i < 196608) {
    out[i] = slots[i];
  } else {
    int j = i - 196608;  // [b][n][s]
    out[i] = attnbuf[j] * invbuf[((j >> 13) << 3) + (j & 7)];
  }
}

extern "C" void kernel_launch(void* const* d_in, const int* in_sizes, int n_in,
                              void* d_out, int out_size, void* d_ws, size_t ws_size,
                              hipStream_t stream) {
  (void)in_sizes; (void)n_in; (void)out_size; (void)ws_size;
  const float* slots0 = (const float*)d_in[0];
  const float* inputs = (const float*)d_in[1];
  const float* Wq = (const float*)d_in[2];
  const float* bq = (const float*)d_in[3];
  const float* Wk = (const float*)d_in[4];
  const float* bk = (const float*)d_in[5];
  const float* Wv = (const float*)d_in[6];
  const float* bv = (const float*)d_in[7];
  const float* g_in = (const float*)d_in[8];
  const float* b_in = (const float*)d_in[9];
  const float* g_s = (const float*)d_in[10];
  const float* b_s = (const float*)d_in[11];
  const float* g_ff = (const float*)d_in[12];
  const float* b_ff = (const float*)d_in[13];
  const float* W1 = (const float*)d_in[14];
  const float* b1 = (const float*)d_in[15];
  const float* W2 = (const float*)d_in[16];
  const float* b2 = (const float*)d_in[17];

  char* p = (char*)d_ws;
  uint32* xh = (uint32*)p;     p += (size_t)32768 * 384 * 4;  // packed bf16 inputs
  float* WkT = (float*)p;      p += (size_t)768 * 768 * 4;
  float* slotsf = (float*)p;   p += 256 * 768 * 4;
  float* qbuf = (float*)p;     p += 256 * 768 * 4;
  float* qkbuf = (float*)p;    p += 256 * 768 * 4;
  float* Sqbuf = (float*)p;    p += 256 * 4;
  float* c0buf = (float*)p;    p += 256 * 4;
  float* attnbuf = (float*)p;  p += (size_t)32768 * 8 * 4;
  float* partials = (float*)p; p += (size_t)16 * 256 * 768 * 4;
  float* A0p = (float*)p;      p += 16 * 256 * 4;
  float* A1p = (float*)p;      p += 16 * 256 * 4;
  float* pooled = (float*)p;   p += 256 * 768 * 4;
  float* invbuf = (float*)p;   p += 256 * 4;
  float* rhobuf = (float*)p;   p += 256 * 4;
  float* updbuf = (float*)p;   p += 256 * 768 * 4;
  float* t1buf = (float*)p;    p += 256 * 768 * 4;

  dim3 ggrid(12, 32);
  setup_k<<<1344, 256, 0, stream>>>(Wk, WkT, slots0, slotsf);
  for (int it = 0; it < 3; ++it) {
    gemv_k<true, 0><<<ggrid, 512, 0, stream>>>(slotsf, Wq, bq, g_s, b_s, nullptr, nullptr,
                                               qbuf);
    gemv_k<false, 1><<<ggrid, 512, 0, stream>>>(qbuf, WkT, nullptr, nullptr, nullptr, nullptr,
                                                nullptr, qkbuf);
    qprep_k<<<64, 256, 0, stream>>>(qbuf, qkbuf, g_in, b_in, bk, Sqbuf, c0buf);
    if (it == 0)
      dotspool_k<true><<<dim3(16, 32), 512, 0, stream>>>(inputs, xh, qkbuf, g_in, Sqbuf,
                                                         c0buf, attnbuf, partials, A0p, A1p);
    else
      dotspool_k<false><<<dim3(16, 32), 512, 0, stream>>>(inputs, xh, qkbuf, g_in, Sqbuf,
                                                          c0buf, attnbuf, partials, A0p, A1p);
    reduce_fix_k<<<256, 256, 0, stream>>>(partials, A0p, A1p, g_in, b_in, pooled,
                                          invbuf, rhobuf);
    gemv_k<false, 2><<<ggrid, 512, 0, stream>>>(pooled, Wv, bv, nullptr, nullptr, invbuf,
                                                rhobuf, updbuf);
    gemv_k<true, 3><<<ggrid, 512, 0, stream>>>(updbuf, W1, b1, g_ff, b_ff, nullptr, nullptr,
                                               t1buf);
    gemv_k<false, 4><<<ggrid, 512, 0, stream>>>(t1buf, W2, b2, nullptr, nullptr, nullptr,
                                                nullptr, slotsf);
  }
  outs_k<<<1792, 256, 0, stream>>>(slotsf, attnbuf, invbuf, (float*)d_out);
}